// Round 2
// baseline (11.295 us; speedup 1.0000x reference)
//
#include <hip/hip_runtime.h>

// Output: coords[p] = (row, col) for p-th lower-triangular entry across all
// t/k blocks, offset by block*k on both coordinates. Pure index generation;
// input x is unused (shape-only in the reference).

__global__ void SparseHead1_coords_kernel(const int* __restrict__ kp,
                                          float2* __restrict__ out,
                                          int npairs_total) {
    int p = blockIdx.x * blockDim.x + threadIdx.x;
    if (p >= npairs_total) return;

    int k = *kp;                     // broadcast read, L2-cached
    int npb = k * (k + 1) / 2;       // pairs per block (36 for k=8)

    int blk = p / npb;
    int m   = p - blk * npb;         // index within block, row-major tril order

    // Invert m = r*(r+1)/2 + c, 0 <= c <= r.
    int r = (int)((sqrtf(8.0f * (float)m + 1.0f) - 1.0f) * 0.5f);
    while ((r + 1) * (r + 2) / 2 <= m) ++r;   // guard float rounding
    while (r * (r + 1) / 2 > m) --r;
    int c = m - r * (r + 1) / 2;

    float base = (float)(blk * k);
    out[p] = make_float2(base + (float)r, base + (float)c);
}

extern "C" void kernel_launch(void* const* d_in, const int* in_sizes, int n_in,
                              void* d_out, int out_size, void* d_ws, size_t ws_size,
                              hipStream_t stream) {
    (void)d_ws; (void)ws_size; (void)n_in; (void)in_sizes;

    const int* kp = (const int*)d_in[1];   // k (scalar as 1-elem int array)
    float2* out = (float2*)d_out;

    int npairs = out_size / 2;             // 36864 for t=8192, k=8
    int block = 256;
    int grid = (npairs + block - 1) / block;

    SparseHead1_coords_kernel<<<grid, block, 0, stream>>>(kp, out, npairs);
}

// Round 3
// 9.326 us; speedup vs baseline: 1.2112x; 1.2112x over previous
//
#include <hip/hip_runtime.h>

// Output: coords[p] = (row, col) for p-th lower-triangular entry across all
// t/k blocks, offset by block*k on both coordinates. Pure index generation;
// input x is unused (shape-only in the reference).
//
// Each thread computes TWO consecutive pairs and emits one float4 store
// (16 B/lane — coalescing sweet spot), halving thread count vs round 2.

__device__ __forceinline__ void tril_invert(int m, int& r, int& c) {
    // Invert m = r*(r+1)/2 + c, 0 <= c <= r.
    r = (int)((sqrtf(8.0f * (float)m + 1.0f) - 1.0f) * 0.5f);
    // Guard float rounding (at most one step either way for small m).
    if ((r + 1) * (r + 2) / 2 <= m) ++r;
    if (r * (r + 1) / 2 > m) --r;
    c = m - r * (r + 1) / 2;
}

__global__ void SparseHead1_coords_kernel(const int* __restrict__ kp,
                                          float* __restrict__ out,
                                          int npairs_total) {
    int i = blockIdx.x * blockDim.x + threadIdx.x;
    int p0 = i * 2;
    if (p0 >= npairs_total) return;

    int k = *kp;                     // broadcast read, L2-cached
    int npb = k * (k + 1) / 2;       // pairs per block (36 for k=8)

    // pair p0
    int blk0 = p0 / npb;
    int m0 = p0 - blk0 * npb;
    int r0, c0;
    tril_invert(m0, r0, c0);
    float base0 = (float)(blk0 * k);

    int p1 = p0 + 1;
    if (p1 < npairs_total) {
        // pair p0+1: same block unless m0 was the last entry of its block
        int blk1 = blk0, m1 = m0 + 1;
        if (m1 == npb) { ++blk1; m1 = 0; }
        int r1, c1;
        tril_invert(m1, r1, c1);
        float base1 = (float)(blk1 * k);

        float4 v = make_float4(base0 + (float)r0, base0 + (float)c0,
                               base1 + (float)r1, base1 + (float)c1);
        *reinterpret_cast<float4*>(&out[p0 * 2]) = v;
    } else {
        // odd tail (not hit for k=8, t=8192; kept for generality)
        out[p0 * 2 + 0] = base0 + (float)r0;
        out[p0 * 2 + 1] = base0 + (float)c0;
    }
}

extern "C" void kernel_launch(void* const* d_in, const int* in_sizes, int n_in,
                              void* d_out, int out_size, void* d_ws, size_t ws_size,
                              hipStream_t stream) {
    (void)d_ws; (void)ws_size; (void)n_in; (void)in_sizes;

    const int* kp = (const int*)d_in[1];   // k (scalar as 1-elem int array)
    float* out = (float*)d_out;

    int npairs = out_size / 2;             // 36864 for t=8192, k=8
    int nthreads = (npairs + 1) / 2;       // 2 pairs per thread
    int block = 256;
    int grid = (nthreads + block - 1) / block;

    SparseHead1_coords_kernel<<<grid, block, 0, stream>>>(kp, out, npairs);
}